// Round 1
// baseline (459.693 us; speedup 1.0000x reference)
//
#include <hip/hip_runtime.h>

// 3x3 VALID cross-correlation (XLA conv: no kernel flip) + bias.
// x: 8192x8192 fp32, w: 3x3, bias scalar -> out: 8190x8190 fp32.
//
// Counter analysis (R0): dur_us 435.9 = 2x 164.3us harness poison fills
// (1 GiB each, fixed) + ~107us conv. Conv moves ~570 MB -> 5.3 TB/s, 84% of
// the 6.3 TB/s mixed-stream ceiling. Remaining levers: 1.125x row-halo
// re-read (18 rows per 16 outputs) and occupancy (64-reg acc live across the
// whole unrolled body).
//
// R1 change: STREAMING-STORE stencil. Each output row is stored immediately
// after its kernel-row-2 contribution, so only 3 accumulator rows (12 floats)
// are live at any point -> register pressure ~independent of strip height.
// That allows RPT=42 (8190 = 42*195 exactly):
//   - halo amplification 44/42 = 1.048x (was 18/16 = 1.125x)
//   - no row clamping, no store masking (all strips fully interior)
//   - lower VGPR -> more waves/SIMD hiding HBM latency at the BW ceiling
// Predicted: conv ~92-100us, dur_us ~418-426.

#define IH 8192
#define IW 8192
#define OH 8190
#define OW 8190
#define RPT 42   // output rows per thread; 8190 = 42 * 195 exactly

// Output row stride 8190 floats -> odd rows are only 8B-aligned.
typedef float float4u __attribute__((ext_vector_type(4), aligned(8)));

__global__ __launch_bounds__(256) void conv2d_3x3_kernel(
    const float* __restrict__ x,
    const float* __restrict__ w,
    const float* __restrict__ bias,
    float* __restrict__ out)
{
    const int c0 = 4 * (blockIdx.x * 256 + threadIdx.x);  // 0..8188, mult of 4
    const int r0 = blockIdx.y * RPT;                      // 0..8148
    const bool tail = (c0 + 6 > IW);  // only the single lane with c0 == 8188

    const float w00 = w[0], w01 = w[1], w02 = w[2];
    const float w10 = w[3], w11 = w[4], w12 = w[5];
    const float w20 = w[6], w21 = w[7], w22 = w[8];
    const float bv = bias[0];

    // acc[d] is *opened* (assigned) at input row d, finished and stored at
    // input row d+2. After full unroll every index is compile-time constant
    // and liveness of each row spans only 3 iterations -> ~12 live acc regs.
    float acc[RPT][4];

    // Branchless tail handling: the float2 companion load sits at +4 floats
    // normally; for the tail lane shift it to -2 (in-bounds, 8B aligned) and
    // zero-select. Tail garbage only feeds the two masked output columns.
    const int g_off = tail ? -2 : 4;

    // Stream input rows r0 .. r0+43. All in-bounds: r0 <= 8148, +43 = 8191.
    // All output rows r0 .. r0+41 <= 8189 valid: no masking anywhere.
#pragma unroll
    for (int d = 0; d < RPT + 2; ++d) {
        const float* rp = x + (size_t)(r0 + d) * IW + c0;

        const float4 f = *(const float4*)rp;            // 16B aligned
        const float2 g = *(const float2*)(rp + g_off);  // >=8B aligned

        float vv[6];
        vv[0] = f.x; vv[1] = f.y; vv[2] = f.z; vv[3] = f.w;
        vv[4] = tail ? 0.0f : g.x;
        vv[5] = tail ? 0.0f : g.y;

        // Input row d feeds: out row d (kernel row 0), out row d-1 (row 1),
        // out row d-2 (row 2, completing it).
        if (d < RPT) {
#pragma unroll
            for (int j = 0; j < 4; ++j)
                acc[d][j] = w00 * vv[j] + w01 * vv[j + 1] + w02 * vv[j + 2];
        }
        if (d >= 1 && d - 1 < RPT) {
#pragma unroll
            for (int j = 0; j < 4; ++j)
                acc[d - 1][j] += w10 * vv[j] + w11 * vv[j + 1] + w12 * vv[j + 2];
        }
        if (d >= 2) {
#pragma unroll
            for (int j = 0; j < 4; ++j)
                acc[d - 2][j] += w20 * vv[j] + w21 * vv[j + 1] + w22 * vv[j + 2];

            // Row r0+d-2 complete: store NOW so its registers die here.
            const int r = r0 + d - 2;
            float* op = out + (size_t)r * OW + c0;
            const float o0 = acc[d - 2][0] + bv;
            const float o1 = acc[d - 2][1] + bv;
            const float o2 = acc[d - 2][2] + bv;
            const float o3 = acc[d - 2][3] + bv;
            if (!tail) {
                float4u o;
                o.x = o0; o.y = o1; o.z = o2; o.w = o3;
                *(float4u*)op = o;
            } else {
                // c0 == 8188: only cols 8188, 8189 exist in the output.
                op[0] = o0;
                op[1] = o1;
            }
        }
    }
}

extern "C" void kernel_launch(void* const* d_in, const int* in_sizes, int n_in,
                              void* d_out, int out_size, void* d_ws, size_t ws_size,
                              hipStream_t stream) {
    const float* x = (const float*)d_in[0];
    const float* w = (const float*)d_in[1];
    const float* b = (const float*)d_in[2];
    float* out     = (float*)d_out;

    dim3 block(256, 1, 1);
    dim3 grid(IW / 4 / 256,   // 8 column-group blocks (8192 cols / 4 / 256)
              OH / RPT, 1);   // 195 row blocks (exact)
    conv2d_3x3_kernel<<<grid, block, 0, stream>>>(x, w, b, out);
}

// Round 2
// 446.353 us; speedup vs baseline: 1.0299x; 1.0299x over previous
//
#include <hip/hip_runtime.h>

// 3x3 VALID cross-correlation (XLA conv: no kernel flip) + bias.
// x: 8192x8192 fp32, w: 3x3, bias scalar -> out: 8190x8190 fp32.
//
// History:
//  R0 (verified best, 435.9us total / ~107us conv): RPT=16 strip per thread,
//     batched store epilogue. Conv at ~5.3 TB/s effective (84% of copy ceiling).
//  R1 (REGRESSED, 459.7us / ~131us conv): RPT=42 streaming-store variant.
//     Lesson: interleaving stores into the load stream wrecks load prefetch
//     distance (stores count in vmcnt -> conservative waitcnt before each
//     store's dependent FMAs). Batched epilogue = pure load+FMA body = deep
//     prefetch. Reverted.
//  R2 (this): exact R0 structure + ONE change: __builtin_nontemporal_store
//     for the output. The 267MB write stream is never re-read; NT stores skip
//     L2 allocation, leaving L2 to the read stream + row-halo reuse
//     (adjacent-row blocks share 2 rows and land on the same XCD since
//     grid.x == 8 == NXCD under linear round-robin dispatch).
//     Predicted: conv ~95-105us, dur_us ~420-430.

#define IH 8192
#define IW 8192
#define OH 8190
#define OW 8190
#define RPT 16   // output rows per thread

// Output row stride 8190 -> odd rows only 8B-aligned; alignment-4 vec type.
typedef float float4u __attribute__((ext_vector_type(4), aligned(4)));

__global__ __launch_bounds__(256) void conv2d_3x3_kernel(
    const float* __restrict__ x,
    const float* __restrict__ w,
    const float* __restrict__ bias,
    float* __restrict__ out)
{
    const int c0 = 4 * (blockIdx.x * 256 + threadIdx.x);  // 0..8188, mult of 4
    const int r0 = blockIdx.y * RPT;
    const bool tail = (c0 + 6 > IW);  // only the single lane with c0 == 8188

    const float w00 = w[0], w01 = w[1], w02 = w[2];
    const float w10 = w[3], w11 = w[4], w12 = w[5];
    const float w20 = w[6], w21 = w[7], w22 = w[8];
    const float bv = bias[0];

    float acc[RPT][4];
#pragma unroll
    for (int d = 0; d < RPT; ++d)
#pragma unroll
        for (int j = 0; j < 4; ++j) acc[d][j] = 0.0f;

    // Branchless tail handling: the float2 companion load sits at +4 floats
    // normally; for the tail lane shift it to -2 (stays in-bounds, 8B aligned)
    // and zero-select the values. Tail garbage only feeds masked output cols.
    const int g_off = tail ? -2 : 4;

    // Stream input rows r0 .. r0+17 (constant trip count -> full unroll).
    // Row index clamped to IH-1 (wave-uniform): clamped rows only contribute
    // to output rows >= OH, which are masked at store.
#pragma unroll
    for (int d = 0; d < RPT + 2; ++d) {
        int i = r0 + d;
        i = (i < IH) ? i : (IH - 1);
        const float* rp = x + (size_t)i * IW + c0;

        const float4 f = *(const float4*)rp;            // 16B aligned
        const float2 g = *(const float2*)(rp + g_off);  // 8B aligned

        float vv[6];
        vv[0] = f.x; vv[1] = f.y; vv[2] = f.z; vv[3] = f.w;
        vv[4] = tail ? 0.0f : g.x;
        vv[5] = tail ? 0.0f : g.y;

        // Input row d contributes: kernel row 0 -> out row d,
        // kernel row 1 -> out row d-1, kernel row 2 -> out row d-2.
        if (d < RPT) {
#pragma unroll
            for (int j = 0; j < 4; ++j)
                acc[d][j] += w00 * vv[j] + w01 * vv[j + 1] + w02 * vv[j + 2];
        }
        if (d >= 1 && d - 1 < RPT) {
#pragma unroll
            for (int j = 0; j < 4; ++j)
                acc[d - 1][j] += w10 * vv[j] + w11 * vv[j + 1] + w12 * vv[j + 2];
        }
        if (d >= 2) {
#pragma unroll
            for (int j = 0; j < 4; ++j)
                acc[d - 2][j] += w20 * vv[j] + w21 * vv[j + 1] + w22 * vv[j + 2];
        }
    }

#pragma unroll
    for (int d = 0; d < RPT; ++d) {
        const int r = r0 + d;
        if (r < OH) {  // wave-uniform (r depends only on blockIdx.y)
            float* op = out + (size_t)r * OW + c0;
            const float o0 = acc[d][0] + bv;
            const float o1 = acc[d][1] + bv;
            const float o2 = acc[d][2] + bv;
            const float o3 = acc[d][3] + bv;
            if (!tail) {
                float4u o;
                o.x = o0; o.y = o1; o.z = o2; o.w = o3;
                __builtin_nontemporal_store(o, (float4u*)op);
            } else {
                // c0 == 8188: only cols 8188, 8189 are valid.
                __builtin_nontemporal_store(o0, op + 0);
                __builtin_nontemporal_store(o1, op + 1);
            }
        }
    }
}

extern "C" void kernel_launch(void* const* d_in, const int* in_sizes, int n_in,
                              void* d_out, int out_size, void* d_ws, size_t ws_size,
                              hipStream_t stream) {
    const float* x = (const float*)d_in[0];
    const float* w = (const float*)d_in[1];
    const float* b = (const float*)d_in[2];
    float* out     = (float*)d_out;

    dim3 block(256, 1, 1);
    dim3 grid(IW / 4 / 256,               // 8 column-group blocks
              (OH + RPT - 1) / RPT, 1);   // 512 row blocks
    conv2d_3x3_kernel<<<grid, block, 0, stream>>>(x, w, b, out);
}